// Round 7
// baseline (17.094 us; speedup 1.0000x reference)
//
#include <hip/hip_runtime.h>
#include <math.h>

// Problem constants (B=256, N=32, D=D1=128, R=O=8)
#define NPAIR 64
#define NCENTER 2048
#define WCAP 48
#define RSLOT 32
#define XROWS 8448                      // 256 center rows + 8192 neighbor rows
#define WSM_BYTES (NPAIR * 32768)       // 64 x (128x128 bf16) swizzled images = 2 MB
#define WSX_OFF   WSM_BYTES
#define WS_NEED   (WSM_BYTES + XROWS * 256)   // + 8448 x 256B bf16 rows = 4.26 MB

typedef __attribute__((ext_vector_type(8))) short bfrag8;
typedef __attribute__((ext_vector_type(8))) unsigned short u16x8;
typedef __attribute__((ext_vector_type(4))) float f32x4;

__device__ __forceinline__ float gelu_f(float v) {
    return 0.5f * v * (1.0f + erff(v * 0.70710678118654752f));
}
__device__ __forceinline__ unsigned short f2bf(float f) {   // RNE fp32->bf16
    unsigned int u = __float_as_uint(f);
    return (unsigned short)((u + 0x7FFFu + ((u >> 16) & 1u)) >> 16);
}

// ---------------- kernel 1: one-time conversion into ws ----------------
// blocks 0..255:   M-convert. blk = pair*4 + quarter(32 cols). Each pair's
//   matrix is written ONCE (not 8x) as the exact swizzled [c][d] bf16 image
//   kernel2 will global_load_lds verbatim:
//   granule(c, dch) @ pair*32768 + c*256 + ((dch ^ key(c))<<4),
//   key(c) = ((c>>3)&7)^(c&7), value = bf16(M[dch*8+j][c]) j=0..7.
// blocks 256..511: x-convert. 33 rows/block -> wsx[row][d] bf16 linear,
//   row<256 = center_h[b], else raw_neighbors[row-256].
__global__ __launch_bounds__(256) void convert_kernel(
    const float* __restrict__ center_h,
    const float* __restrict__ raw_neighbors,
    const float* __restrict__ Mg,
    char* __restrict__ ws)
{
    const int t = threadIdx.x;
    if (blockIdx.x < 256) {
        const int pair = blockIdx.x >> 2, q = blockIdx.x & 3;
        const int dblk = t >> 4;                 // 0..15 (with wave: 4w+(lane>>4))
        const int cbase = q * 32 + (t & 15) * 2; // 2 cols per thread
        const float* bp = Mg + pair * 16384 + dblk * 8 * 128 + cbase;
        float g0[8], g1[8];
        #pragma unroll
        for (int r = 0; r < 8; ++r) {            // 128B-coalesced per 16-lane group
            const float2 v = *(const float2*)(bp + r * 128);
            g0[r] = v.x; g1[r] = v.y;
        }
        char* wm = ws + pair * 32768;
        #pragma unroll
        for (int cc = 0; cc < 2; ++cc) {
            const int c = cbase + cc;
            u16x8 w;
            #pragma unroll
            for (int j = 0; j < 8; ++j) w[j] = f2bf(cc ? g1[j] : g0[j]);
            const int key = ((c >> 3) & 7) ^ (c & 7);
            *(u16x8*)(wm + c * 256 + ((dblk ^ key) << 4)) = w;
        }
    } else {
        const int xb = blockIdx.x - 256;
        char* wx = ws + WSX_OFF;
        for (int i = t; i < 33 * 16; i += 256) {
            const int row = xb * 33 + (i >> 4);
            const int ch = i & 15;
            const float* src = (row < 256) ? center_h + row * 128
                                           : raw_neighbors + (row - 256) * 128;
            const float4 a = *(const float4*)(src + ch * 8);
            const float4 b = *(const float4*)(src + ch * 8 + 4);
            u16x8 w;
            w[0] = f2bf(a.x); w[1] = f2bf(a.y); w[2] = f2bf(a.z); w[3] = f2bf(a.w);
            w[4] = f2bf(b.x); w[5] = f2bf(b.y); w[6] = f2bf(b.z); w[7] = f2bf(b.w);
            *(u16x8*)(wx + row * 256 + (ch << 4)) = w;
        }
    }
}

// ---------------- kernel 2: grouped MFMA GEMV ----------------
// 512 blocks = 64 pairs x 8 slices (pair = blk&63 -> XCD L2 affinity).
// M staged via 8x global_load_lds dwordx4 (verbatim swizzled image, async,
// zero VALU). x rows gathered bf16 via per-lane-source global_load_lds with
// source-side XOR pre-swizzle (LDS dest linear). MFMA math = round-6 verbatim.
__global__ __launch_bounds__(256) void mfma_kernel(
    const char* __restrict__ ws,
    const float* __restrict__ bias,
    const int* __restrict__ center_o,
    const int* __restrict__ s_types,
    const int* __restrict__ o_types,
    float* __restrict__ out)
{
    __shared__ __align__(16) unsigned short Mbt[128 * 128];  // 32 KB swizzled [c][d]
    __shared__ __align__(16) unsigned short Xs[RSLOT * 128]; // 8 KB swizzled [slot][d]
    __shared__ int list[4 * WCAP];
    __shared__ int cnts[4];
    __shared__ int rowid[RSLOT];

    const int t    = threadIdx.x;
    const int wave = t >> 6, lane = t & 63;
    const int pair = blockIdx.x & 63, slice = blockIdx.x >> 6;
    const int r0 = pair >> 3, o0 = pair & 7;

    // scan loads first (FIFO vmcnt: ballot waits only on these)
    const int4 svv = ((const int4*)s_types)[slice * 256 + t];
    const int4 ovv = ((const int4*)o_types)[slice * 256 + t];
    const int my_b  = slice * 32 + wave * 8 + (lane & 7);
    const int my_co = center_o[my_b];

    // async-stage the pre-converted M image (32KB, linear verbatim)
    {
        const char* src = ws + pair * 32768;
        #pragma unroll
        for (int i = 0; i < 8; ++i) {
            const int off = (i * 256 + t) * 16;
            __builtin_amdgcn_global_load_lds(
                (const __attribute__((address_space(1))) void*)(src + off),
                (__attribute__((address_space(3))) void*)((char*)Mbt + off),
                16, 0, 0);
        }
    }

    // ballot compaction (deterministic; proven R4-R6)
    int cw = 0;
    {
        const bool match = (lane < 8) && (my_co == o0);
        const unsigned long long mk = __ballot(match);
        const int pre = __builtin_amdgcn_mbcnt_hi(
            (unsigned)(mk >> 32), __builtin_amdgcn_mbcnt_lo((unsigned)mk, 0));
        if (match) {
            const int pos = cw + pre;
            if (pos < WCAP) list[wave * WCAP + pos] = my_b * 8 + r0;
        }
        cw += __popcll(mk);
    }
    {
        const int ss[4] = { svv.x, svv.y, svv.z, svv.w };
        const int oo[4] = { ovv.x, ovv.y, ovv.z, ovv.w };
        const int base_nid = slice * 1024 + t * 4;
        #pragma unroll
        for (int j = 0; j < 4; ++j) {
            const int s = ss[j] < 0 ? 0 : ss[j];
            const int o = oo[j] < 0 ? 0 : oo[j];
            const bool match = (s == r0) & (o == o0);
            const unsigned long long mk = __ballot(match);
            const int pre = __builtin_amdgcn_mbcnt_hi(
                (unsigned)(mk >> 32), __builtin_amdgcn_mbcnt_lo((unsigned)mk, 0));
            if (match) {
                const int pos = cw + pre;
                if (pos < WCAP) list[wave * WCAP + pos] = NCENTER + base_nid + j;
            }
            cw += __popcll(mk);
            if (cw > WCAP) cw = WCAP;
        }
    }
    if (lane == 0) cnts[wave] = cw;
    __syncthreads();   // lists visible (also drains: Mbt staged)

    const int c0_ = cnts[0], c1_ = cnts[1], c2_ = cnts[2];
    const int cnt = c0_ + c1_ + c2_ + cnts[3];

    const int lo16 = lane & 15, hi4 = lane >> 4;
    const int cA = wave * 32 + lo16;
    const int cB = cA + 16;
    const float bvA = bias[pair * 128 + cA];
    const float bvB = bias[pair * 128 + cB];
    const int keyA = ((cA >> 3) & 7) ^ (cA & 7);
    const int keyB = ((cB >> 3) & 7) ^ (cB & 7);
    const int rsw  = lo16 & 7;
    const char* wx = ws + WSX_OFF;

    for (int base = 0; base < cnt; base += RSLOT) {
        const int csz = (cnt - base < RSLOT) ? (cnt - base) : RSLOT;

        if (t < RSLOT) {
            int id = -1;
            int a = base + t;
            if (a < cnt) {
                int sw = 0;
                if (a >= c0_) { a -= c0_; sw = 1;
                    if (a >= c1_) { a -= c1_; sw = 2;
                        if (a >= c2_) { a -= c2_; sw = 3; } } }
                id = list[sw * WCAP + a];
            }
            rowid[t] = id;
        }
        __syncthreads();   // rowid visible

        // gather x rows (bf16) via global_load_lds; source-side XOR swizzle,
        // LDS dest linear: dest granule (slot,ch) <- wsx granule (ch^(slot&7))
        #pragma unroll
        for (int i = 0; i < 2; ++i) {
            const int flat = i * 256 + t;          // 32 slots x 16 granules
            const int slot = flat >> 4, ch = flat & 15;
            const int id = rowid[slot];
            if (id >= 0) {
                const int xrow = (id < NCENTER) ? (id >> 3) : (256 + id - NCENTER);
                const char* src = wx + xrow * 256 + ((ch ^ (slot & 7)) << 4);
                __builtin_amdgcn_global_load_lds(
                    (const __attribute__((address_space(1))) void*)src,
                    (__attribute__((address_space(3))) void*)((char*)Xs + slot * 256 + (ch << 4)),
                    16, 0, 0);
            }
        }
        __syncthreads();   // drains vmcnt: Xs (and Mbt) ready

        // MFMA (round-6 verified fragment scheme, bit-for-bit)
        f32x4 accA = {bvA, bvA, bvA, bvA};
        f32x4 accB = {bvB, bvB, bvB, bvB};
        f32x4 accC = accA, accD = accB;
        const int rowA = lo16, rowB = 16 + lo16;
        #pragma unroll
        for (int k = 0; k < 4; ++k) {
            const int dch = 4 * k + hi4;
            const bfrag8 aA = *(const bfrag8*)((const char*)Xs  + rowA * 256 + ((dch ^ rsw)  << 4));
            const bfrag8 aB = *(const bfrag8*)((const char*)Xs  + rowB * 256 + ((dch ^ rsw)  << 4));
            const bfrag8 b0 = *(const bfrag8*)((const char*)Mbt + cA   * 256 + ((dch ^ keyA) << 4));
            const bfrag8 b1 = *(const bfrag8*)((const char*)Mbt + cB   * 256 + ((dch ^ keyB) << 4));
            accA = __builtin_amdgcn_mfma_f32_16x16x32_bf16(aA, b0, accA, 0, 0, 0);
            accB = __builtin_amdgcn_mfma_f32_16x16x32_bf16(aA, b1, accB, 0, 0, 0);
            accC = __builtin_amdgcn_mfma_f32_16x16x32_bf16(aB, b0, accC, 0, 0, 0);
            accD = __builtin_amdgcn_mfma_f32_16x16x32_bf16(aB, b1, accD, 0, 0, 0);
        }

        #pragma unroll
        for (int j = 0; j < 4; ++j) {
            const int sA = hi4 * 4 + j;
            if (sA < csz) {
                const int gid = rowid[sA];
                out[gid * 128 + cA] = gelu_f(accA[j]);
                out[gid * 128 + cB] = gelu_f(accB[j]);
            }
            const int sB = 16 + hi4 * 4 + j;
            if (sB < csz) {
                const int gid = rowid[sB];
                out[gid * 128 + cA] = gelu_f(accC[j]);
                out[gid * 128 + cB] = gelu_f(accD[j]);
            }
        }
        __syncthreads();   // protect Xs/rowid before next chunk
    }
}

// ---------------- round-6 fused kernel: fallback if ws too small ----------------
__global__ __launch_bounds__(256) void fused_kernel(
    const float* __restrict__ center_h,
    const float* __restrict__ raw_neighbors,
    const float* __restrict__ Mg,
    const float* __restrict__ bias,
    const int* __restrict__ center_o,
    const int* __restrict__ s_types,
    const int* __restrict__ o_types,
    float* __restrict__ out)
{
    __shared__ __align__(16) unsigned short Mbt[128 * 128];
    __shared__ __align__(16) unsigned short Xs[RSLOT * 128];
    __shared__ int list[4 * WCAP];
    __shared__ int cnts[4];
    __shared__ int rowid[RSLOT];

    const int t    = threadIdx.x;
    const int wave = t >> 6, lane = t & 63;
    const int pair = blockIdx.x & 63, slice = blockIdx.x >> 6;
    const int r0 = pair >> 3, o0 = pair & 7;

    const int4 svv = ((const int4*)s_types)[slice * 256 + t];
    const int4 ovv = ((const int4*)o_types)[slice * 256 + t];
    const int my_b  = slice * 32 + wave * 8 + (lane & 7);
    const int my_co = center_o[my_b];

    {
        const int dblk = t >> 4, cblk = t & 15;
        const float* bp = Mg + pair * 16384 + dblk * 8 * 128 + cblk * 8;
        float gg[8][8];
        #pragma unroll
        for (int r = 0; r < 8; ++r) {
            const float4 x0 = *(const float4*)(bp + r * 128);
            const float4 x1 = *(const float4*)(bp + r * 128 + 4);
            gg[r][0] = x0.x; gg[r][1] = x0.y; gg[r][2] = x0.z; gg[r][3] = x0.w;
            gg[r][4] = x1.x; gg[r][5] = x1.y; gg[r][6] = x1.z; gg[r][7] = x1.w;
        }
        #pragma unroll
        for (int i = 0; i < 8; ++i) {
            u16x8 w;
            #pragma unroll
            for (int j = 0; j < 8; ++j) w[j] = f2bf(gg[j][i]);
            const int c  = cblk * 8 + i;
            const int sl = (dblk ^ (cblk & 7) ^ i) << 4;
            *(u16x8*)((char*)Mbt + c * 256 + sl) = w;
        }
    }

    int cw = 0;
    {
        const bool match = (lane < 8) && (my_co == o0);
        const unsigned long long mk = __ballot(match);
        const int pre = __builtin_amdgcn_mbcnt_hi(
            (unsigned)(mk >> 32), __builtin_amdgcn_mbcnt_lo((unsigned)mk, 0));
        if (match) {
            const int pos = cw + pre;
            if (pos < WCAP) list[wave * WCAP + pos] = my_b * 8 + r0;
        }
        cw += __popcll(mk);
    }
    {
        const int ss[4] = { svv.x, svv.y, svv.z, svv.w };
        const int oo[4] = { ovv.x, ovv.y, ovv.z, ovv.w };
        const int base_nid = slice * 1024 + t * 4;
        #pragma unroll
        for (int j = 0; j < 4; ++j) {
            const int s = ss[j] < 0 ? 0 : ss[j];
            const int o = oo[j] < 0 ? 0 : oo[j];
            const bool match = (s == r0) & (o == o0);
            const unsigned long long mk = __ballot(match);
            const int pre = __builtin_amdgcn_mbcnt_hi(
                (unsigned)(mk >> 32), __builtin_amdgcn_mbcnt_lo((unsigned)mk, 0));
            if (match) {
                const int pos = cw + pre;
                if (pos < WCAP) list[wave * WCAP + pos] = NCENTER + base_nid + j;
            }
            cw += __popcll(mk);
            if (cw > WCAP) cw = WCAP;
        }
    }
    if (lane == 0) cnts[wave] = cw;
    __syncthreads();

    const int c0_ = cnts[0], c1_ = cnts[1], c2_ = cnts[2];
    const int cnt = c0_ + c1_ + c2_ + cnts[3];

    const int lo16 = lane & 15, hi4 = lane >> 4;
    const int cA = wave * 32 + lo16;
    const int cB = cA + 16;
    const float bvA = bias[pair * 128 + cA];
    const float bvB = bias[pair * 128 + cB];
    const int keyA = ((cA >> 3) & 7) ^ (cA & 7);
    const int keyB = ((cB >> 3) & 7) ^ (cB & 7);
    const int rsw  = lo16 & 7;

    for (int base = 0; base < cnt; base += RSLOT) {
        const int csz = (cnt - base < RSLOT) ? (cnt - base) : RSLOT;

        if (t < RSLOT) {
            int id = -1;
            int a = base + t;
            if (a < cnt) {
                int sw = 0;
                if (a >= c0_) { a -= c0_; sw = 1;
                    if (a >= c1_) { a -= c1_; sw = 2;
                        if (a >= c2_) { a -= c2_; sw = 3; } } }
                id = list[sw * WCAP + a];
            }
            rowid[t] = id;
        }
        __syncthreads();

        #pragma unroll
        for (int i = 0; i < 2; ++i) {
            const int flat = i * 256 + t;
            const int row = flat >> 4, ch = flat & 15;
            const int id = rowid[row];
            u16x8 w = {0, 0, 0, 0, 0, 0, 0, 0};
            if (id >= 0) {
                const float* xp = (id < NCENTER) ? center_h + (id >> 3) * 128
                                                 : raw_neighbors + (id - NCENTER) * 128;
                const float4 x0 = *(const float4*)(xp + ch * 8);
                const float4 x1 = *(const float4*)(xp + ch * 8 + 4);
                w[0] = f2bf(x0.x); w[1] = f2bf(x0.y); w[2] = f2bf(x0.z); w[3] = f2bf(x0.w);
                w[4] = f2bf(x1.x); w[5] = f2bf(x1.y); w[6] = f2bf(x1.z); w[7] = f2bf(x1.w);
            }
            *(u16x8*)((char*)Xs + row * 256 + ((ch ^ (row & 7)) << 4)) = w;
        }
        __syncthreads();

        f32x4 accA = {bvA, bvA, bvA, bvA};
        f32x4 accB = {bvB, bvB, bvB, bvB};
        f32x4 accC = accA, accD = accB;
        const int rowA = lo16, rowB = 16 + lo16;
        #pragma unroll
        for (int k = 0; k < 4; ++k) {
            const int dch = 4 * k + hi4;
            const bfrag8 aA = *(const bfrag8*)((const char*)Xs  + rowA * 256 + ((dch ^ rsw)  << 4));
            const bfrag8 aB = *(const bfrag8*)((const char*)Xs  + rowB * 256 + ((dch ^ rsw)  << 4));
            const bfrag8 b0 = *(const bfrag8*)((const char*)Mbt + cA   * 256 + ((dch ^ keyA) << 4));
            const bfrag8 b1 = *(const bfrag8*)((const char*)Mbt + cB   * 256 + ((dch ^ keyB) << 4));
            accA = __builtin_amdgcn_mfma_f32_16x16x32_bf16(aA, b0, accA, 0, 0, 0);
            accB = __builtin_amdgcn_mfma_f32_16x16x32_bf16(aA, b1, accB, 0, 0, 0);
            accC = __builtin_amdgcn_mfma_f32_16x16x32_bf16(aB, b0, accC, 0, 0, 0);
            accD = __builtin_amdgcn_mfma_f32_16x16x32_bf16(aB, b1, accD, 0, 0, 0);
        }

        #pragma unroll
        for (int j = 0; j < 4; ++j) {
            const int sA = hi4 * 4 + j;
            if (sA < csz) {
                const int gid = rowid[sA];
                out[gid * 128 + cA] = gelu_f(accA[j]);
                out[gid * 128 + cB] = gelu_f(accB[j]);
            }
            const int sB = 16 + hi4 * 4 + j;
            if (sB < csz) {
                const int gid = rowid[sB];
                out[gid * 128 + cA] = gelu_f(accC[j]);
                out[gid * 128 + cB] = gelu_f(accD[j]);
            }
        }
        __syncthreads();
    }
}

extern "C" void kernel_launch(void* const* d_in, const int* in_sizes, int n_in,
                              void* d_out, int out_size, void* d_ws, size_t ws_size,
                              hipStream_t stream) {
    const float* center_h      = (const float*)d_in[0];
    const float* raw_neighbors = (const float*)d_in[1];
    const float* M             = (const float*)d_in[2];
    const float* bias          = (const float*)d_in[3];
    const int*   center_o      = (const int*)d_in[4];
    const int*   s_types       = (const int*)d_in[5];
    const int*   o_types       = (const int*)d_in[6];
    float* out = (float*)d_out;

    if (ws_size >= (size_t)WS_NEED) {
        char* ws = (char*)d_ws;
        convert_kernel<<<dim3(512), dim3(256), 0, stream>>>(
            center_h, raw_neighbors, M, ws);
        mfma_kernel<<<dim3(NPAIR * 8), dim3(256), 0, stream>>>(
            ws, bias, center_o, s_types, o_types, out);
    } else {
        fused_kernel<<<dim3(NPAIR * 8), dim3(256), 0, stream>>>(
            center_h, raw_neighbors, M, bias, center_o, s_types, o_types, out);
    }
}

// Round 8
// 11.748 us; speedup vs baseline: 1.4551x; 1.4551x over previous
//
#include <hip/hip_runtime.h>
#include <math.h>

// Problem constants (B=256, N=32, D=D1=128, R=O=8)
#define NPAIR 64
#define NCENTER 2048
#define WCAP 48
#define RSLOT 32

typedef __attribute__((ext_vector_type(8))) short bfrag8;
typedef __attribute__((ext_vector_type(8))) unsigned short u16x8;
typedef __attribute__((ext_vector_type(4))) float f32x4;

__device__ __forceinline__ float gelu_f(float v) {
    return 0.5f * v * (1.0f + erff(v * 0.70710678118654752f));
}
__device__ __forceinline__ unsigned short f2bf(float f) {   // RNE fp32->bf16
    unsigned int u = __float_as_uint(f);
    return (unsigned short)((u + 0x7FFFu + ((u >> 16) & 1u)) >> 16);
}

// ONE dispatch, 1024 blocks = 64 pairs x 2 col-halves x 8 slices.
// pair = blk & 63 (XCD L2 affinity: blk%8 == pair%8). Per block:
//  - convert its pair's HALF-matrix (64 cols x 128 d) fp32->bf16 transposed
//    into LDS [c][d], 4-bit XOR swizzle g = dch ^ (c&15): conflict-free b128
//    reads AND writes (R6's 3-bit key left an 8-way read conflict).
//  - ballot-bin its slice's rows (b in [32s,+32), nid in [1024s,+1024)) —
//    deterministic (fixed lane->id map, mbcnt prefix), proven R4-R6.
//  - per 32-row chunk: stage x rows bf16 into LDS (g = ch ^ (slot&15)),
//    then mfma_f32_16x16x32_bf16: each wave 1 col-tile x 2 row-tiles x 4 k.
// 4 blocks/CU (25KB LDS, launch_bounds 256,4) for latency hiding.
__global__ __launch_bounds__(256, 4) void fused_kernel(
    const float* __restrict__ center_h,
    const float* __restrict__ raw_neighbors,
    const float* __restrict__ Mg,
    const float* __restrict__ bias,
    const int* __restrict__ center_o,
    const int* __restrict__ s_types,
    const int* __restrict__ o_types,
    float* __restrict__ out)
{
    __shared__ __align__(16) unsigned short Mbt[64 * 128];   // 16KB [c_loc][d]
    __shared__ __align__(16) unsigned short Xs[RSLOT * 128]; // 8KB  [slot][d]
    __shared__ int list[4 * WCAP];
    __shared__ int cnts[4];
    __shared__ int rowid[RSLOT];

    const int t    = threadIdx.x;
    const int wave = t >> 6, lane = t & 63;
    const int pair = blockIdx.x & 63;
    const int rest = blockIdx.x >> 6;        // 0..15
    const int ch   = rest & 1;               // col-half
    const int slice = rest >> 1;             // 0..7
    const int r0 = pair >> 3, o0 = pair & 7;

    // --- scan loads first (FIFO vmcnt: ballot waits only on these)
    const int4 svv = ((const int4*)s_types)[slice * 256 + t];
    const int4 ovv = ((const int4*)o_types)[slice * 256 + t];
    const int my_b  = slice * 32 + wave * 8 + (lane & 7);
    const int my_co = center_o[my_b];

    // --- M half-matrix loads: thread (dblk=t>>4, lane16=t&15) reads cols
    // c_loc = 16*i + lane16 (i<4), d = dblk*8+r (r<8). Strided dwords:
    // each instr = 4x 64B segments; granule writes are lane-distinct.
    const int lane16 = t & 15, dblk = t >> 4;
    float g[4][8];
    {
        const float* mp = Mg + pair * 16384 + (dblk * 8) * 128 + ch * 64;
        #pragma unroll
        for (int i = 0; i < 4; ++i)
            #pragma unroll
            for (int r = 0; r < 8; ++r)
                g[i][r] = mp[r * 128 + 16 * i + lane16];
    }

    // --- ballot compaction (deterministic; proven R4-R6 verbatim)
    int cw = 0;
    {
        const bool match = (lane < 8) && (my_co == o0);
        const unsigned long long mk = __ballot(match);
        const int pre = __builtin_amdgcn_mbcnt_hi(
            (unsigned)(mk >> 32), __builtin_amdgcn_mbcnt_lo((unsigned)mk, 0));
        if (match) {
            const int pos = cw + pre;
            if (pos < WCAP) list[wave * WCAP + pos] = my_b * 8 + r0;
        }
        cw += __popcll(mk);
    }
    {
        const int ss[4] = { svv.x, svv.y, svv.z, svv.w };
        const int oo[4] = { ovv.x, ovv.y, ovv.z, ovv.w };
        const int base_nid = slice * 1024 + t * 4;
        #pragma unroll
        for (int j = 0; j < 4; ++j) {
            const int s = ss[j] < 0 ? 0 : ss[j];
            const int o = oo[j] < 0 ? 0 : oo[j];
            const bool match = (s == r0) & (o == o0);
            const unsigned long long mk = __ballot(match);
            const int pre = __builtin_amdgcn_mbcnt_hi(
                (unsigned)(mk >> 32), __builtin_amdgcn_mbcnt_lo((unsigned)mk, 0));
            if (match) {
                const int pos = cw + pre;
                if (pos < WCAP) list[wave * WCAP + pos] = NCENTER + base_nid + j;
            }
            cw += __popcll(mk);
            if (cw > WCAP) cw = WCAP;
        }
    }
    if (lane == 0) cnts[wave] = cw;

    // --- pack + transposed swizzled write of M half into LDS
    // granule dch at col c holds d = dch*8+j; write g_idx = dblk ^ (c&15);
    // per instr c&15 = lane16 -> all 16 granule slots distinct: conflict-free.
    #pragma unroll
    for (int i = 0; i < 4; ++i) {
        const int c = 16 * i + lane16;
        u16x8 w;
        #pragma unroll
        for (int r = 0; r < 8; ++r) w[r] = f2bf(g[i][r]);
        *(u16x8*)((char*)Mbt + c * 256 + ((dblk ^ lane16) << 4)) = w;
    }
    __syncthreads();   // Mbt + lists + cnts visible

    const int c0_ = cnts[0], c1_ = cnts[1], c2_ = cnts[2];
    const int cnt = c0_ + c1_ + c2_ + cnts[3];

    const int lo16 = lane & 15, hi4 = lane >> 4;
    const int c_loc = wave * 16 + lo16;          // local col 0..63
    const int colg  = ch * 64 + c_loc;           // global col
    const float bv = bias[pair * 128 + colg];

    for (int base = 0; base < cnt; base += RSLOT) {
        const int csz = (cnt - base < RSLOT) ? (cnt - base) : RSLOT;

        if (t < RSLOT) {
            int id = -1;
            int a = base + t;
            if (a < cnt) {
                int sw = 0;
                if (a >= c0_) { a -= c0_; sw = 1;
                    if (a >= c1_) { a -= c1_; sw = 2;
                        if (a >= c2_) { a -= c2_; sw = 3; } } }
                id = list[sw * WCAP + a];
            }
            rowid[t] = id;
        }
        __syncthreads();   // rowid visible

        // stage x rows (bf16, swizzled g = chg ^ (slot&15)); pad rows zero.
        // per instr: 16-lane cluster has slot fixed, chg 0..15 -> distinct.
        #pragma unroll
        for (int i = 0; i < 2; ++i) {
            const int flat = i * 256 + t;          // 32 slots x 16 granules
            const int slot = flat >> 4, chg = flat & 15;
            const int id = rowid[slot];
            u16x8 w = {0, 0, 0, 0, 0, 0, 0, 0};
            if (id >= 0) {
                const float* xp = (id < NCENTER) ? center_h + (id >> 3) * 128
                                                 : raw_neighbors + (id - NCENTER) * 128;
                const float4 x0 = *(const float4*)(xp + chg * 8);
                const float4 x1 = *(const float4*)(xp + chg * 8 + 4);
                w[0] = f2bf(x0.x); w[1] = f2bf(x0.y); w[2] = f2bf(x0.z); w[3] = f2bf(x0.w);
                w[4] = f2bf(x1.x); w[5] = f2bf(x1.y); w[6] = f2bf(x1.z); w[7] = f2bf(x1.w);
            }
            *(u16x8*)((char*)Xs + slot * 256 + ((chg ^ (slot & 15)) << 4)) = w;
        }
        __syncthreads();   // Xs visible

        // MFMA: A-frag lane(row=lo16/hi4): k = hi4*8+j -> granule dch = 4k+hi4.
        // rowA & 15 == rowB & 15 == lo16 -> shared swizzle key.
        f32x4 accA = {bv, bv, bv, bv};
        f32x4 accC = accA;
        #pragma unroll
        for (int k = 0; k < 4; ++k) {
            const int dch = 4 * k + hi4;
            const int gsl = (dch ^ lo16) << 4;
            const bfrag8 aA = *(const bfrag8*)((const char*)Xs  + lo16 * 256 + gsl);
            const bfrag8 aB = *(const bfrag8*)((const char*)Xs  + (16 + lo16) * 256 + gsl);
            const bfrag8 b0 = *(const bfrag8*)((const char*)Mbt + c_loc * 256 + gsl);
            accA = __builtin_amdgcn_mfma_f32_16x16x32_bf16(aA, b0, accA, 0, 0, 0);
            accC = __builtin_amdgcn_mfma_f32_16x16x32_bf16(aB, b0, accC, 0, 0, 0);
        }

        // epilogue: D col = lane&15 (-> colg), row-in-tile = hi4*4 + j
        #pragma unroll
        for (int j = 0; j < 4; ++j) {
            const int sA = hi4 * 4 + j;
            if (sA < csz) out[rowid[sA] * 128 + colg] = gelu_f(accA[j]);
            const int sB = 16 + hi4 * 4 + j;
            if (sB < csz) out[rowid[sB] * 128 + colg] = gelu_f(accC[j]);
        }
        __syncthreads();   // protect Xs/rowid before next chunk
    }
}

extern "C" void kernel_launch(void* const* d_in, const int* in_sizes, int n_in,
                              void* d_out, int out_size, void* d_ws, size_t ws_size,
                              hipStream_t stream) {
    const float* center_h      = (const float*)d_in[0];
    const float* raw_neighbors = (const float*)d_in[1];
    const float* M             = (const float*)d_in[2];
    const float* bias          = (const float*)d_in[3];
    const int*   center_o      = (const int*)d_in[4];
    const int*   s_types       = (const int*)d_in[5];
    const int*   o_types       = (const int*)d_in[6];
    float* out = (float*)d_out;

    fused_kernel<<<dim3(NPAIR * 16), dim3(256), 0, stream>>>(
        center_h, raw_neighbors, M, bias, center_o, s_types, o_types, out);
}